// Round 3
// baseline (108.354 us; speedup 1.0000x reference)
//
#include <hip/hip_runtime.h>
#include <cstddef>

#define Bq 16
#define TEq 128
#define TDq 128
#define Hq 256

#define kC2  2.8853900817779268f  /* 2*log2(e) */
#define kL2E 1.4426950408889634f

static __device__ __forceinline__ float fast_rcp(float x) {
#if __has_builtin(__builtin_amdgcn_rcpf)
    return __builtin_amdgcn_rcpf(x);
#else
    return 1.0f / x;
#endif
}

static __device__ __forceinline__ float fast_exp2(float x) {
#if __has_builtin(__builtin_amdgcn_exp2f)
    return __builtin_amdgcn_exp2f(x);
#else
    return exp2f(x);
#endif
}

// ---------------------------------------------------------------------------
// K1: orthogonalize. Exclusive cumsum over TE split into 8 chunks of 16 per
// (b,h); chunk partials exchanged via LDS; x held in registers (loaded once).
// Block = 256 thr = 8 chunks x 32 h. Grid = (H/32, B) = (8,16) = 128 blocks.
// ---------------------------------------------------------------------------
__global__ __launch_bounds__(256) void k_ortho(const float* __restrict__ enc,
                                               float* __restrict__ out) {
    const int b = blockIdx.y;
    const int hg = blockIdx.x;            // 0..7
    const int tid = threadIdx.x;
    const int hl = tid & 31;
    const int ck = tid >> 5;              // chunk 0..7 (16 t each)
    const int h = (hg << 5) + hl;

    __shared__ float sums[8][33];

    const float* p = enc + ((size_t)b * TEq + ck * 16) * Hq + h;
    float xs[16];
#pragma unroll
    for (int i = 0; i < 16; ++i) xs[i] = p[(size_t)i * Hq];
    float tot = 0.0f;
#pragma unroll
    for (int i = 0; i < 16; ++i) tot += xs[i];
    sums[ck][hl] = tot;
    __syncthreads();

    float s = 0.0f;
    for (int c = 0; c < ck; ++c) s += sums[c][hl];   // exclusive chunk prefix

    float* q = out + ((size_t)b * TEq + ck * 16) * Hq + h;
#pragma unroll
    for (int i = 0; i < 16; ++i) {
        const float x = xs[i];
        const float r = (x * s) / (x * x);           // exact div, matches ref
        q[(size_t)i * Hq] = x - r * x;
        s += x;
    }
}

// ---------------------------------------------------------------------------
// K2: two GEMMs, C = A[2048,256] @ W[256,256].  z=0: was = enc_o@W_a (scaled
// by 2*log2e), z=1: uah = dec@U_a.
// 64x64 tile / 256 thr / 4x4 per thread / only A staged in LDS (one
// ds_read_b128 per k-step); B rows streamed from global (L1/L2-hot weight
// matrix, all lanes of a quarter-wave share the row) with an 8-row register
// double buffer. Grid (4,32,2) = 256 blocks.
// ---------------------------------------------------------------------------
__global__ __launch_bounds__(256) void k_gemm2(const float* __restrict__ A0,
                                               const float* __restrict__ A1,
                                               const float* __restrict__ W0,
                                               const float* __restrict__ W1,
                                               float* __restrict__ Cw,
                                               float* __restrict__ Cu) {
    const int z = blockIdx.z;
    const float* __restrict__ A = z ? A1 : A0;
    const float* __restrict__ W = z ? W1 : W0;
    float* __restrict__ C = z ? Cu : Cw;
    const float scale = z ? 1.0f : kC2;

    const int bm = blockIdx.y * 64;
    const int bn = blockIdx.x * 64;

    __shared__ float sA[32][68];   // [k][m]; stride 68 (mod32=4) -> 2-way max on b128 (free)

    const int tid = threadIdx.x;
    const int tx = tid & 15;          // n: 4 cols each
    const int ty = tid >> 4;          // m: 4 rows each
    const int sr = tid & 63;          // staging row 0..63
    const int sc = (tid >> 6) << 2;   // staging k-quad 0,4,8,12

    const float* __restrict__ Bp = W + bn + (tx << 2);
    const float* __restrict__ Ap = A + (size_t)(bm + sr) * Hq;

    float acc[4][4] = {};
    float4 bcur[8], bnxt[8];

#pragma unroll
    for (int i = 0; i < 8; ++i)
        bcur[i] = *(const float4*)(Bp + (size_t)i * Hq);

    for (int kt = 0; kt < 8; ++kt) {
        const int k0 = kt * 32;
        const float4 a0 = *(const float4*)(Ap + k0 + sc);
        const float4 a1 = *(const float4*)(Ap + k0 + sc + 16);
        __syncthreads();
        sA[sc + 0][sr] = a0.x;  sA[sc + 1][sr] = a0.y;
        sA[sc + 2][sr] = a0.z;  sA[sc + 3][sr] = a0.w;
        sA[sc + 16][sr] = a1.x; sA[sc + 17][sr] = a1.y;
        sA[sc + 18][sr] = a1.z; sA[sc + 19][sr] = a1.w;
        __syncthreads();

#pragma unroll
        for (int kg = 0; kg < 4; ++kg) {
            const int nk = k0 + kg * 8 + 8;       // next group's first k (uniform)
            if (nk < Hq) {
#pragma unroll
                for (int i = 0; i < 8; ++i)
                    bnxt[i] = *(const float4*)(Bp + (size_t)(nk + i) * Hq);
            }
#pragma unroll
            for (int i = 0; i < 8; ++i) {
                const float4 a4 = *(const float4*)&sA[kg * 8 + i][ty << 2];
                const float af[4] = {a4.x, a4.y, a4.z, a4.w};
                const float bf[4] = {bcur[i].x, bcur[i].y, bcur[i].z, bcur[i].w};
#pragma unroll
                for (int r = 0; r < 4; ++r)
#pragma unroll
                    for (int c = 0; c < 4; ++c)
                        acc[r][c] = fmaf(af[r], bf[c], acc[r][c]);
            }
            if (nk < Hq) {
#pragma unroll
                for (int i = 0; i < 8; ++i) bcur[i] = bnxt[i];
            }
        }
    }

#pragma unroll
    for (int r = 0; r < 4; ++r) {
        float4 o;
        o.x = acc[r][0] * scale;
        o.y = acc[r][1] * scale;
        o.z = acc[r][2] * scale;
        o.w = acc[r][3] * scale;
        *(float4*)(C + (size_t)(bm + (ty << 2) + r) * Hq + bn + (tx << 2)) = o;
    }
}

// ---------------------------------------------------------------------------
// K3: energies + softmax + context. Block = (b, 2 d's); wave w: d-local=w>>1,
// e-half=w&1. 4 sub-groups of 16 lanes per wave each own one e at a time,
// each lane covers 16 h (4 interleaved float4 chunks).
// tanh(z) = 1 - 2/(exp2(C2*z)+1); energy = Vsum - 2*sum(v*r).
// was pre-scaled by C2 (K2 epilogue); uah scaled at LDS load.
// Grid (TD/2, B) = (64,16) = 1024 blocks -> 4 blocks/CU, 16 waves/CU.
// ---------------------------------------------------------------------------
__global__ __launch_bounds__(256) void k_attn(const float* __restrict__ was,
                                              const float* __restrict__ uah,
                                              const float* __restrict__ enc_o,
                                              const float* __restrict__ Va,
                                              float* __restrict__ c_out,
                                              float* __restrict__ e_out) {
    const int b = blockIdx.y;
    const int d0 = blockIdx.x << 1;

    __shared__ float uahs[2][Hq];
    __shared__ float Vs[Hq];
    __shared__ float wts[2][TEq];   // energies, then softmax weights

    const int tid = threadIdx.x;
    const int w = tid >> 6;         // wave 0..3
    const int lane = tid & 63;
    const int dl = w >> 1;          // d-local 0..1
    const int half = w & 1;         // e-half

    Vs[tid] = Va[tid];
#pragma unroll
    for (int j = 0; j < 2; ++j)
        uahs[j][tid] = uah[((size_t)b * TDq + d0 + j) * Hq + tid] * kC2;
    __syncthreads();

    const int g = lane >> 4;        // sub-group 0..3
    const int ll = lane & 15;

    // Vsum (all lanes, redundant across waves)
    float vs = Vs[lane] + Vs[lane + 64] + Vs[lane + 128] + Vs[lane + 192];
#pragma unroll
    for (int m = 1; m <= 32; m <<= 1) vs += __shfl_xor(vs, m);

    // preload u/v fragments: h = c*64 + ll*4 + i
    float4 ur[4], vr[4];
#pragma unroll
    for (int c = 0; c < 4; ++c) {
        ur[c] = *(const float4*)&uahs[dl][c * 64 + (ll << 2)];
        vr[c] = *(const float4*)&Vs[c * 64 + (ll << 2)];
    }

    const float* wasb = was + (size_t)b * TEq * Hq;

    for (int ei = 0; ei < 16; ++ei) {
        const int e = (half << 6) + (g << 4) + ei;
        const float* wp = wasb + (size_t)e * Hq + (ll << 2);
        float acc = 0.0f;
#pragma unroll
        for (int c = 0; c < 4; ++c) {
            const float4 wv = *(const float4*)(wp + c * 64);
            const float wf[4] = {wv.x, wv.y, wv.z, wv.w};
            const float uf[4] = {ur[c].x, ur[c].y, ur[c].z, ur[c].w};
            const float vf[4] = {vr[c].x, vr[c].y, vr[c].z, vr[c].w};
#pragma unroll
            for (int i = 0; i < 4; ++i) {
                const float s = wf[i] + uf[i];          // C2*(was+uah)
                const float t = fast_exp2(s);           // e^{2z}
                const float r = fast_rcp(t + 1.0f);
                acc = fmaf(vf[i], r, acc);
            }
        }
        acc += __shfl_xor(acc, 1);
        acc += __shfl_xor(acc, 2);
        acc += __shfl_xor(acc, 4);
        acc += __shfl_xor(acc, 8);
        if (ll == 0) wts[dl][e] = vs - 2.0f * acc;
    }
    __syncthreads();

    // softmax: waves 0,1 handle d = d0 + w
    if (w < 2) {
        const float v0 = wts[w][lane];
        const float v1 = wts[w][lane + 64];
        float mx = fmaxf(v0, v1);
#pragma unroll
        for (int m = 1; m <= 32; m <<= 1) mx = fmaxf(mx, __shfl_xor(mx, m));
        const float e0 = fast_exp2((v0 - mx) * kL2E);
        const float e1 = fast_exp2((v1 - mx) * kL2E);
        float sm = e0 + e1;
#pragma unroll
        for (int m = 1; m <= 32; m <<= 1) sm += __shfl_xor(sm, m);
        const float inv = fast_rcp(sm);
        const float w0 = e0 * inv;
        const float w1 = e1 * inv;
        wts[w][lane] = w0;
        wts[w][lane + 64] = w1;
        const size_t eb = ((size_t)b * TDq + d0 + w) * TEq;
        e_out[eb + lane] = w0;
        e_out[eb + lane + 64] = w1;
    }
    __syncthreads();

    // context: c[b,d0+j,h=tid] = sum_e wts[j][e] * enc_o[b,e,h]
    // wts read as float4 (b128) to cut LDS instruction count 4x.
    float a0 = 0.0f, a1 = 0.0f;
    const float* ep = enc_o + (size_t)b * TEq * Hq + tid;
#pragma unroll 4
    for (int e4 = 0; e4 < TEq; e4 += 4) {
        const float4 w0v = *(const float4*)&wts[0][e4];
        const float4 w1v = *(const float4*)&wts[1][e4];
        const float x0 = ep[(size_t)(e4 + 0) * Hq];
        const float x1 = ep[(size_t)(e4 + 1) * Hq];
        const float x2 = ep[(size_t)(e4 + 2) * Hq];
        const float x3 = ep[(size_t)(e4 + 3) * Hq];
        a0 = fmaf(w0v.x, x0, a0); a1 = fmaf(w1v.x, x0, a1);
        a0 = fmaf(w0v.y, x1, a0); a1 = fmaf(w1v.y, x1, a1);
        a0 = fmaf(w0v.z, x2, a0); a1 = fmaf(w1v.z, x2, a1);
        a0 = fmaf(w0v.w, x3, a0); a1 = fmaf(w1v.w, x3, a1);
    }
    const size_t cb = ((size_t)b * TDq + d0) * Hq + tid;
    c_out[cb] = a0;
    c_out[cb + Hq] = a1;
}

extern "C" void kernel_launch(void* const* d_in, const int* in_sizes, int n_in,
                              void* d_out, int out_size, void* d_ws, size_t ws_size,
                              hipStream_t stream) {
    const float* enc = (const float*)d_in[0];   // [16,128,256]
    const float* dec = (const float*)d_in[1];   // [16,128,256]
    const float* Wa  = (const float*)d_in[2];   // [256,256]
    const float* Ua  = (const float*)d_in[3];   // [256,256]
    const float* Va  = (const float*)d_in[4];   // [256,1]

    float* c_out = (float*)d_out;                        // [16,128,256]
    float* e_out = c_out + (size_t)Bq * TDq * Hq;        // [16,128,128]

    float* enc_o = (float*)d_ws;                         // 2 MB
    float* wasb  = enc_o + (size_t)Bq * TEq * Hq;        // 2 MB (pre-scaled by 2*log2e)
    float* uahb  = wasb + (size_t)Bq * TEq * Hq;         // 2 MB

    k_ortho<<<dim3(Hq / 32, Bq), dim3(256), 0, stream>>>(enc, enc_o);
    k_gemm2<<<dim3(Hq / 64, (Bq * TEq) / 64, 2), dim3(256), 0, stream>>>(
        enc_o, dec, Wa, Ua, wasb, uahb);
    k_attn<<<dim3(TDq / 2, Bq), dim3(256), 0, stream>>>(
        wasb, uahb, enc_o, Va, c_out, e_out);
}